// Round 1
// baseline (648.596 us; speedup 1.0000x reference)
//
#include <hip/hip_runtime.h>
#include <hip/hip_bf16.h>

typedef __attribute__((ext_vector_type(8))) short bf16x8;
typedef __attribute__((ext_vector_type(4))) float f32x4;
typedef __attribute__((ext_vector_type(4))) short s16x4;
typedef unsigned short ushort_t;

__device__ __forceinline__ unsigned short f2bf(float f) {
    unsigned int u = __float_as_uint(f);
    u = (u + 0x7FFFu + ((u >> 16) & 1u)) >> 16;   // RNE
    return (unsigned short)u;
}
__device__ __forceinline__ float fast_sigmoid(float x) {
    return 1.0f / (1.0f + __expf(-x));
}
__device__ __forceinline__ float fast_tanh(float x) {
    x = fminf(fmaxf(x, -15.0f), 15.0f);
    float e = __expf(2.0f * x);
    return (e - 1.0f) / (e + 1.0f);
}
__device__ __forceinline__ f32x4 mfma16(bf16x8 a, bf16x8 b, f32x4 c) {
    return __builtin_amdgcn_mfma_f32_16x16x32_bf16(a, b, c, 0, 0, 0);
}

// ---- weight fp32 -> bf16 conversion (runs every launch; ws is re-poisoned) ----
// layout in ws (bf16 elems): W1 128x512 @0, W2 64x128 @65536, W3 128x64 @73728,
// WIH 512x640 @81920, FCW 128x128 @409600. total 425984 elems = 851968 B.
__global__ void convert_w_kernel(const float* __restrict__ w1, const float* __restrict__ w2,
                                 const float* __restrict__ w3, const float* __restrict__ wih,
                                 const float* __restrict__ fcw, ushort_t* __restrict__ outw) {
    int i = blockIdx.x * 256 + threadIdx.x;   // grid covers exactly 425984
    float v;
    if (i < 65536)       v = w1[i];
    else if (i < 73728)  v = w2[i - 65536];
    else if (i < 81920)  v = w3[i - 73728];
    else if (i < 409600) v = wih[i - 81920];
    else                 v = fcw[i - 409600];
    outw[i] = f2bf(v);
}

#define XS_LD 520   // 512 + 8 pad; row stride 260 dw -> 8 lanes per 4-bank group (throughput-ideal)
#define D1_LD 136
#define D2_LD 72
#define D3_LD 136
#define HS_LD 136
// M=32 rows/block. LDS = 32*(520+136+72)*2 = 46592 B -> 3 blocks/CU, 24 waves (75% occ).
// Aliasing (both barrier-protected):
//   d3s aliases d1s : d1s last read in phase2, strictly before the d2s-ready barrier;
//                     d3s written in phase3, strictly after it.
//   hs  aliases xs  : xs last read in phase4 part A, strictly before the d3s-ready
//                     barrier; hs written strictly after it.

__global__ __launch_bounds__(512, 6) void fused_mlp_lstm_kernel(
    const float* __restrict__ x,
    const float* __restrict__ b1, const float* __restrict__ b2, const float* __restrict__ b3,
    const float* __restrict__ b_ih, const float* __restrict__ b_hh,
    const float* __restrict__ fc_b,
    const ushort_t* __restrict__ wbf,
    float* __restrict__ out)
{
    __shared__ ushort_t sm[32 * (XS_LD + D1_LD + D2_LD)];
    ushort_t* xs  = sm;
    ushort_t* d1s = xs  + 32 * XS_LD;
    ushort_t* d2s = d1s + 32 * D1_LD;
    ushort_t* d3s = d1s;   // alias (see above)
    ushort_t* hs  = xs;    // alias (see above)

    const ushort_t* W1  = wbf;            // (128,512)
    const ushort_t* W2  = wbf + 65536;    // (64,128)
    const ushort_t* W3  = wbf + 73728;    // (128,64)
    const ushort_t* WIH = wbf + 81920;    // (512,640)
    const ushort_t* FCW = wbf + 409600;   // (128,128)

    const int t  = threadIdx.x;
    const int w  = t >> 6;        // wave 0..7
    const int l  = t & 63;
    const int q  = l >> 4;        // quad 0..3
    const int lm = l & 15;
    const int ko = q * 8;
    const int n0 = w * 16;        // this wave's N slice (phases 1,3,4,5)
    const long rowBase = (long)blockIdx.x * 32;

    // ---- phase1 B preload, first half (kk 0..7): 32 VGPRs, in flight during staging ----
    bf16x8 bw1a[8];
    #pragma unroll
    for (int kk = 0; kk < 8; ++kk)
        bw1a[kk] = *(const bf16x8*)(W1 + (n0 + lm) * 512 + kk * 32 + ko);

    // ---- stage-a: x cols [0,256) -> bf16 LDS ----
    const float4* xv = (const float4*)(x + rowBase * 512);
    #pragma unroll
    for (int i = 0; i < 4; ++i) {
        int u = t + i * 512;              // 0..2047
        int row = u >> 6, c4 = u & 63;    // 64 float4s per half-row, rows 0..31
        float4 v = xv[row * 128 + c4];
        s16x4 pk;
        pk.x = (short)f2bf(v.x); pk.y = (short)f2bf(v.y);
        pk.z = (short)f2bf(v.z); pk.w = (short)f2bf(v.w);
        *(s16x4*)(xs + row * XS_LD + c4 * 4) = pk;
    }
    __syncthreads();

    // ---- stage-b loads (cols [256,512)) into regs; overlap with phase1a ----
    float4 vb[4];
    #pragma unroll
    for (int i = 0; i < 4; ++i) {
        int u = t + i * 512;
        vb[i] = xv[(u >> 6) * 128 + 64 + (u & 63)];
    }

    // ---- phase1a: kk 0..7 (uses xs cols < 256) ----
    f32x4 a1[2] = {{0,0,0,0},{0,0,0,0}};
    #pragma unroll
    for (int kk = 0; kk < 8; ++kk) {
        #pragma unroll
        for (int s = 0; s < 2; ++s) {
            bf16x8 fa = *(const bf16x8*)(xs + (s * 16 + lm) * XS_LD + kk * 32 + ko);
            a1[s] = mfma16(fa, bw1a[kk], a1[s]);
        }
    }

    // ---- stage-b writes (cols >= 256: disjoint from phase1a reads, no barrier yet) ----
    #pragma unroll
    for (int i = 0; i < 4; ++i) {
        int u = t + i * 512;
        int row = u >> 6, c4 = u & 63;
        s16x4 pk;
        pk.x = (short)f2bf(vb[i].x); pk.y = (short)f2bf(vb[i].y);
        pk.z = (short)f2bf(vb[i].z); pk.w = (short)f2bf(vb[i].w);
        *(s16x4*)(xs + row * XS_LD + (64 + c4) * 4) = pk;
    }

    // ---- phase1 B preload, second half (kk 8..15) ----
    bf16x8 bw1b[8];
    #pragma unroll
    for (int kk = 0; kk < 8; ++kk)
        bw1b[kk] = *(const bf16x8*)(W1 + (n0 + lm) * 512 + (8 + kk) * 32 + ko);
    __syncthreads();

    // ---- phase1b: kk 8..15, bias+relu, store d1s ----
    #pragma unroll
    for (int kk = 0; kk < 8; ++kk) {
        #pragma unroll
        for (int s = 0; s < 2; ++s) {
            bf16x8 fa = *(const bf16x8*)(xs + (s * 16 + lm) * XS_LD + (8 + kk) * 32 + ko);
            a1[s] = mfma16(fa, bw1b[kk], a1[s]);
        }
    }
    {
        float bv = b1[n0 + lm];
        #pragma unroll
        for (int s = 0; s < 2; ++s)
            #pragma unroll
            for (int r = 0; r < 4; ++r)
                d1s[(s * 16 + q * 4 + r) * D1_LD + n0 + lm] = f2bf(fmaxf(a1[s][r] + bv, 0.0f));
    }

    // ---- phase2 B preload (global; before barrier) ----
    const int w4 = w & 3, half = w >> 2;   // wave -> (col slice, row half) for N=64 phase
    const int n2 = w4 * 16;
    bf16x8 bw2[4];
    #pragma unroll
    for (int kk = 0; kk < 4; ++kk)
        bw2[kk] = *(const bf16x8*)(W2 + (n2 + lm) * 128 + kk * 32 + ko);
    __syncthreads();   // d1s ready

    // ---- phase2: d2 = relu(d1 @ W2^T + b2)  M=32 N=64 K=128, one 16x16 tile/wave ----
    {
        f32x4 a2 = {0,0,0,0};
        #pragma unroll
        for (int kk = 0; kk < 4; ++kk) {
            bf16x8 fa = *(const bf16x8*)(d1s + (half * 16 + lm) * D1_LD + kk * 32 + ko);
            a2 = mfma16(fa, bw2[kk], a2);
        }
        float bv = b2[n2 + lm];
        #pragma unroll
        for (int r = 0; r < 4; ++r)
            d2s[(half * 16 + q * 4 + r) * D2_LD + n2 + lm] = f2bf(fmaxf(a2[r] + bv, 0.0f));
    }

    // ---- phase3 + phase4-chunk0 B preloads (global; before barrier) ----
    const int rI = n0, rG = 256 + n0, rO = 384 + n0;
    bf16x8 bw3[2];
    #pragma unroll
    for (int kk = 0; kk < 2; ++kk)
        bw3[kk] = *(const bf16x8*)(W3 + (n0 + lm) * 64 + kk * 32 + ko);
    bf16x8 bi0[2], bg0[2], bo0[2];
    #pragma unroll
    for (int j = 0; j < 2; ++j) {
        bi0[j] = *(const bf16x8*)(WIH + (rI + lm) * 640 + j * 32 + ko);
        bg0[j] = *(const bf16x8*)(WIH + (rG + lm) * 640 + j * 32 + ko);
        bo0[j] = *(const bf16x8*)(WIH + (rO + lm) * 640 + j * 32 + ko);
    }
    __syncthreads();   // d2s ready (all d1s reads done -> d3s alias safe)

    // ---- phase3: d3 = d2 @ W3^T + b3  (no relu) ----
    {
        f32x4 a3[2] = {{0,0,0,0},{0,0,0,0}};
        #pragma unroll
        for (int kk = 0; kk < 2; ++kk) {
            #pragma unroll
            for (int s = 0; s < 2; ++s) {
                bf16x8 fa = *(const bf16x8*)(d2s + (s * 16 + lm) * D2_LD + kk * 32 + ko);
                a3[s] = mfma16(fa, bw3[kk], a3[s]);
            }
        }
        float bv = b3[n0 + lm];
        #pragma unroll
        for (int s = 0; s < 2; ++s)
            #pragma unroll
            for (int r = 0; r < 4; ++r)
                d3s[(s * 16 + q * 4 + r) * D3_LD + n0 + lm] = f2bf(a3[s][r] + bv);
    }
    // no barrier: phase4 part A reads only xs (stable until hs writes, which are
    // after the d3s-ready barrier below)

    // ---- phase4 part A: gates vs x, kk 0..15 in chunks of 2 (keeps VGPRs < 84) ----
    f32x4 aI[2] = {{0,0,0,0},{0,0,0,0}};
    f32x4 aG[2] = {{0,0,0,0},{0,0,0,0}};
    f32x4 aO[2] = {{0,0,0,0},{0,0,0,0}};
    #pragma unroll
    for (int j = 0; j < 2; ++j) {
        bf16x8 fa[2];
        #pragma unroll
        for (int s = 0; s < 2; ++s)
            fa[s] = *(const bf16x8*)(xs + (s * 16 + lm) * XS_LD + j * 32 + ko);
        #pragma unroll
        for (int s = 0; s < 2; ++s) {
            aI[s] = mfma16(fa[s], bi0[j], aI[s]);
            aG[s] = mfma16(fa[s], bg0[j], aG[s]);
            aO[s] = mfma16(fa[s], bo0[j], aO[s]);
        }
    }
    #pragma unroll
    for (int c = 1; c < 8; ++c) {
        bf16x8 bi[2], bg[2], bo[2];
        #pragma unroll
        for (int j2 = 0; j2 < 2; ++j2) {
            int j = c * 2 + j2;
            bi[j2] = *(const bf16x8*)(WIH + (rI + lm) * 640 + j * 32 + ko);
            bg[j2] = *(const bf16x8*)(WIH + (rG + lm) * 640 + j * 32 + ko);
            bo[j2] = *(const bf16x8*)(WIH + (rO + lm) * 640 + j * 32 + ko);
        }
        #pragma unroll
        for (int j2 = 0; j2 < 2; ++j2) {
            int j = c * 2 + j2;
            bf16x8 fa[2];
            #pragma unroll
            for (int s = 0; s < 2; ++s)
                fa[s] = *(const bf16x8*)(xs + (s * 16 + lm) * XS_LD + j * 32 + ko);
            #pragma unroll
            for (int s = 0; s < 2; ++s) {
                aI[s] = mfma16(fa[s], bi[j2], aI[s]);
                aG[s] = mfma16(fa[s], bg[j2], aG[s]);
                aO[s] = mfma16(fa[s], bo[j2], aO[s]);
            }
        }
    }

    // ---- phase4 part B: gates vs d3 (WIH cols 512..639), chunked 2+2 ----
    {
        bf16x8 biB[2], bgB[2], boB[2];
        #pragma unroll
        for (int j = 0; j < 2; ++j) {
            biB[j] = *(const bf16x8*)(WIH + (rI + lm) * 640 + 512 + j * 32 + ko);
            bgB[j] = *(const bf16x8*)(WIH + (rG + lm) * 640 + 512 + j * 32 + ko);
            boB[j] = *(const bf16x8*)(WIH + (rO + lm) * 640 + 512 + j * 32 + ko);
        }
        __syncthreads();   // d3s ready; all xs reads complete -> hs alias safe
        #pragma unroll
        for (int j = 0; j < 2; ++j) {
            bf16x8 fa[2];
            #pragma unroll
            for (int s = 0; s < 2; ++s)
                fa[s] = *(const bf16x8*)(d3s + (s * 16 + lm) * D3_LD + j * 32 + ko);
            #pragma unroll
            for (int s = 0; s < 2; ++s) {
                aI[s] = mfma16(fa[s], biB[j], aI[s]);
                aG[s] = mfma16(fa[s], bgB[j], aG[s]);
                aO[s] = mfma16(fa[s], boB[j], aO[s]);
            }
        }
        bf16x8 biB2[2], bgB2[2], boB2[2];
        #pragma unroll
        for (int j = 0; j < 2; ++j) {
            biB2[j] = *(const bf16x8*)(WIH + (rI + lm) * 640 + 512 + (2 + j) * 32 + ko);
            bgB2[j] = *(const bf16x8*)(WIH + (rG + lm) * 640 + 512 + (2 + j) * 32 + ko);
            boB2[j] = *(const bf16x8*)(WIH + (rO + lm) * 640 + 512 + (2 + j) * 32 + ko);
        }
        #pragma unroll
        for (int j = 0; j < 2; ++j) {
            bf16x8 fa[2];
            #pragma unroll
            for (int s = 0; s < 2; ++s)
                fa[s] = *(const bf16x8*)(d3s + (s * 16 + lm) * D3_LD + (2 + j) * 32 + ko);
            #pragma unroll
            for (int s = 0; s < 2; ++s) {
                aI[s] = mfma16(fa[s], biB2[j], aI[s]);
                aG[s] = mfma16(fa[s], bgB2[j], aG[s]);
                aO[s] = mfma16(fa[s], boB2[j], aO[s]);
            }
        }
    }

    // ---- LSTM elementwise (f-gate dead, h == ctx since seq=1) -> hs (aliases xs) ----
    {
        float biasI = b_ih[rI + lm] + b_hh[rI + lm];
        float biasG = b_ih[rG + lm] + b_hh[rG + lm];
        float biasO = b_ih[rO + lm] + b_hh[rO + lm];
        #pragma unroll
        for (int s = 0; s < 2; ++s)
            #pragma unroll
            for (int r = 0; r < 4; ++r) {
                float c = fast_sigmoid(aI[s][r] + biasI) * fast_tanh(aG[s][r] + biasG);
                float h = fast_sigmoid(aO[s][r] + biasO) * fast_tanh(c);
                hs[(s * 16 + q * 4 + r) * HS_LD + n0 + lm] = f2bf(h);
            }
    }
    // ---- phase5 B preload before hs barrier ----
    bf16x8 bw5[4];
    #pragma unroll
    for (int kk = 0; kk < 4; ++kk)
        bw5[kk] = *(const bf16x8*)(FCW + (n0 + lm) * 128 + kk * 32 + ko);
    __syncthreads();   // hs ready

    // ---- phase5: out = h @ fc_w^T + fc_b ----
    {
        f32x4 a5[2] = {{0,0,0,0},{0,0,0,0}};
        #pragma unroll
        for (int kk = 0; kk < 4; ++kk) {
            #pragma unroll
            for (int s = 0; s < 2; ++s) {
                bf16x8 fa = *(const bf16x8*)(hs + (s * 16 + lm) * HS_LD + kk * 32 + ko);
                a5[s] = mfma16(fa, bw5[kk], a5[s]);
            }
        }
        float bv = fc_b[n0 + lm];
        #pragma unroll
        for (int s = 0; s < 2; ++s)
            #pragma unroll
            for (int r = 0; r < 4; ++r)
                out[(rowBase + s * 16 + q * 4 + r) * 128 + n0 + lm] = a5[s][r] + bv;
    }
}

extern "C" void kernel_launch(void* const* d_in, const int* in_sizes, int n_in,
                              void* d_out, int out_size, void* d_ws, size_t ws_size,
                              hipStream_t stream) {
    const float* x    = (const float*)d_in[0];
    const float* w1   = (const float*)d_in[1];
    const float* b1   = (const float*)d_in[2];
    const float* w2   = (const float*)d_in[3];
    const float* b2   = (const float*)d_in[4];
    const float* w3   = (const float*)d_in[5];
    const float* b3   = (const float*)d_in[6];
    const float* wih  = (const float*)d_in[7];
    // d_in[8] = W_hh (dead: h_prev == 0), d_in[11]/[12] = attn (dead: seq len 1)
    const float* b_ih = (const float*)d_in[9];
    const float* b_hh = (const float*)d_in[10];
    const float* fcw  = (const float*)d_in[13];
    const float* fcb  = (const float*)d_in[14];

    ushort_t* wbf = (ushort_t*)d_ws;   // 851968 B of bf16 weights
    float* out = (float*)d_out;

    convert_w_kernel<<<1664, 256, 0, stream>>>(w1, w2, w3, wih, fcw, wbf);
    fused_mlp_lstm_kernel<<<131072 / 32, 512, 0, stream>>>(
        x, b1, b2, b3, b_ih, b_hh, fcb, wbf, out);
}